// Round 11
// baseline (283.665 us; speedup 1.0000x reference)
//
#include <hip/hip_runtime.h>
#include <hip/hip_bf16.h>
#include <math.h>

#define EMBED  512
#define HEADS  2
#define HDIM   256
#define NTEXT  64
#define NWORD  32
#define NVID   128
#define NFRM   64

typedef __attribute__((ext_vector_type(8))) short      short8;    // 8 bf16 = A/B frag
typedef __attribute__((ext_vector_type(8))) unsigned short ushort8;
typedef __attribute__((ext_vector_type(4))) float      float4v;   // C/D frag
typedef __attribute__((ext_vector_type(4))) unsigned short ushort4v;

__device__ __forceinline__ unsigned short f2bf(float x) {
    __hip_bfloat16 h = __float2bfloat16(x);
    return *(unsigned short*)&h;
}
__device__ __forceinline__ float bf2f(unsigned short u) {
    __hip_bfloat16 h = *(__hip_bfloat16*)&u;
    return __bfloat162float(h);
}

// ===========================================================================
// proj_qkv (r9-verified): unified projection GEMM. Grid (288, 8), 256 thr.
//   mb <  32 : q  = (text @ Wq^T + bq)/16 -> bf16 row-major [2048][512] (d_out)
//   mb < 160 : K  -> frag-major Kgf[h][a][nt4][kq8][l64][j8]
//   else     : V  -> frag-major Vgf[h][a][ntd16][kqv2][l64][j8]
// ===========================================================================
__global__ __launch_bounds__(256)
void proj_qkv(const float* __restrict__ text, const float* __restrict__ video,
              const float* __restrict__ Wq, const float* __restrict__ bq,
              const float* __restrict__ Wk, const float* __restrict__ bk,
              const float* __restrict__ Wv, const float* __restrict__ bv,
              unsigned short* __restrict__ qout,
              unsigned short* __restrict__ Kgf, unsigned short* __restrict__ Vgf) {
    const int mb = blockIdx.x, nb = blockIdx.y;
    const int bj = nb * 64;
    const float *A, *W, *bias;
    int op, arow, a = 0;
    if (mb < 32)       { op = 0; A = text;  W = Wq; bias = bq; arow = mb * 64; }
    else if (mb < 160) { op = 1; A = video; W = Wk; bias = bk; a = mb - 32;  arow = a * 64; }
    else               { op = 2; A = video; W = Wv; bias = bv; a = mb - 160; arow = a * 64; }

    __shared__ __align__(16) unsigned char smem[64 * 40 * 2 * 2];  // 10240 B
    unsigned short (*Ab)[40] = (unsigned short (*)[40])smem;
    unsigned short (*Wb)[40] = (unsigned short (*)[40])(smem + 5120);
    unsigned short (*Eb)[72] = (unsigned short (*)[72])smem;

    const int tid = threadIdx.x;
    const int w = tid >> 6, lane = tid & 63;
    const int lm = lane & 15, qd = lane >> 4;

    float4v acc[4];
    #pragma unroll
    for (int nt = 0; nt < 4; ++nt) acc[nt] = (float4v){0.f, 0.f, 0.f, 0.f};

    for (int k0 = 0; k0 < 512; k0 += 32) {
        #pragma unroll
        for (int it = 0; it < 2; ++it) {
            const int s = tid + it * 256;
            const int r = s >> 3, c4 = (s & 7) * 4;
            float4v fa = *(const float4v*)&A[(size_t)(arow + r) * 512 + k0 + c4];
            float4v fw = *(const float4v*)&W[(size_t)(bj + r) * 512 + k0 + c4];
            *(ushort4v*)&Ab[r][c4] = (ushort4v){f2bf(fa.x), f2bf(fa.y), f2bf(fa.z), f2bf(fa.w)};
            *(ushort4v*)&Wb[r][c4] = (ushort4v){f2bf(fw.x), f2bf(fw.y), f2bf(fw.z), f2bf(fw.w)};
        }
        __syncthreads();
        const short8 af = *(const short8*)&Ab[w * 16 + lm][qd * 8];
        #pragma unroll
        for (int nt = 0; nt < 4; ++nt) {
            const short8 bf = *(const short8*)&Wb[nt * 16 + lm][qd * 8];
            acc[nt] = __builtin_amdgcn_mfma_f32_16x16x32_bf16(af, bf, acc[nt], 0, 0, 0);
        }
        __syncthreads();
    }

    if (op == 0) {
        #pragma unroll
        for (int nt = 0; nt < 4; ++nt) {
            const int c = bj + nt * 16 + lm;
            const float bb = bias[c];
            #pragma unroll
            for (int reg = 0; reg < 4; ++reg) {
                const int r = arow + w * 16 + qd * 4 + reg;
                qout[(size_t)r * 512 + c] = f2bf((acc[nt][reg] + bb) * 0.0625f);
            }
        }
        return;
    }

    const int h = bj >> 8;
    const int bj_rel = bj & 255;

    if (op == 1) {
        #pragma unroll
        for (int nt = 0; nt < 4; ++nt) {
            const int dl = nt * 16 + lm;
            const float bb = bias[bj + dl];
            #pragma unroll
            for (int reg = 0; reg < 4; ++reg)
                Eb[w * 16 + qd * 4 + reg][dl] = f2bf(acc[nt][reg] + bb);
        }
        __syncthreads();
        const size_t base = ((size_t)(h * 128 + a)) * 16384;
        #pragma unroll
        for (int i = 0; i < 2; ++i) {
            const int s = tid + i * 256;
            const int ntf = s >> 7, kqr = (s >> 6) & 1, l = s & 63;
            const int v = ntf * 16 + (l & 15);
            const int dl = kqr * 32 + (l >> 4) * 8;
            ushort8 val = *(const ushort8*)&Eb[v][dl];
            *(ushort8*)&Kgf[base + ((size_t)(ntf * 8 + (bj_rel >> 5) + kqr) * 64 + l) * 8] = val;
        }
    } else {
        #pragma unroll
        for (int nt = 0; nt < 4; ++nt) {
            const int dl = nt * 16 + lm;
            const float bb = bias[bj + dl];
            #pragma unroll
            for (int reg = 0; reg < 4; ++reg)
                Eb[dl][w * 16 + qd * 4 + reg] = f2bf(acc[nt][reg] + bb);
        }
        __syncthreads();
        const size_t base = ((size_t)(h * 128 + a)) * 16384;
        #pragma unroll
        for (int i = 0; i < 2; ++i) {
            const int s = tid + i * 256;
            const int ntr = s >> 7, kqv = (s >> 6) & 1, l = s & 63;
            const int dl = ntr * 16 + (l & 15);
            const int v0 = kqv * 32 + (l >> 4) * 8;
            ushort8 val = *(const ushort8*)&Eb[dl][v0];
            *(ushort8*)&Vgf[base + ((size_t)(((bj_rel >> 4) + ntr) * 2 + kqv) * 64 + l) * 8] = val;
        }
    }
}

// ===========================================================================
// attn16: grid (8 chunks, 2 h, 16 text-groups) = 256 blocks, 256 thr, 2/CU.
// Wave w owns text b = zb*4 + w; loops 16 vids of chunk c (r9-verified math).
// mode 0: plain-store bf16 partial into partg[c] (disjoint rows; NO atomics).
// mode 1: atomicAdd fp32 into acc (8.4M atomics, half of r9).
// ===========================================================================
__global__ __launch_bounds__(256, 2)
void attn16(const unsigned short* __restrict__ Kgf,
            const unsigned short* __restrict__ Vgf,
            const unsigned short* __restrict__ q,   // bf16, pre-scaled 1/16
            unsigned short* __restrict__ partg,     // [8][2048][512] bf16 (mode 0)
            float* __restrict__ acc,                // [2048][512] fp32 (mode 1)
            int mode) {
    const int c = blockIdx.x;
    const int h = blockIdx.y;
    const int zb = blockIdx.z;
    const int tid = threadIdx.x;
    const int w = tid >> 6, lane = tid & 63;
    const int lm = lane & 15, qd = lane >> 4;
    const int b = zb * 4 + w;

    __shared__ __align__(16) unsigned short KfL[16384];   // 32 KB
    __shared__ __align__(16) unsigned short VfL[16384];   // 32 KB
    __shared__ __align__(16) unsigned short PfL[8192];    // 16 KB (4 KB/wave)
    const int wpf = w * 2048;

    short8 qf[2][8];
    #pragma unroll
    for (int mt = 0; mt < 2; ++mt)
        #pragma unroll
        for (int kq = 0; kq < 8; ++kq)
            qf[mt][kq] = *(const short8*)
                &q[((size_t)(b * 32 + mt * 16 + lm)) * 512 + h * 256 + kq * 32 + qd * 8];

    float4v pacc[2][16];
    #pragma unroll
    for (int mt = 0; mt < 2; ++mt)
        #pragma unroll
        for (int nt = 0; nt < 16; ++nt) pacc[mt][nt] = (float4v){0.f, 0.f, 0.f, 0.f};

    for (int ai = 0; ai < 16; ++ai) {
        const int a = c * 16 + ai;
        __syncthreads();
        const size_t kb = ((size_t)(h * 128 + a)) * 16384;
        #pragma unroll
        for (int i = 0; i < 8; ++i) {
            const int s = tid + i * 256;
            *(ushort8*)&KfL[s * 8] = *(const ushort8*)&Kgf[kb + (size_t)s * 8];
            *(ushort8*)&VfL[s * 8] = *(const ushort8*)&Vgf[kb + (size_t)s * 8];
        }
        __syncthreads();

        float4v lacc[2][4];
        #pragma unroll
        for (int mt = 0; mt < 2; ++mt)
            #pragma unroll
            for (int nt = 0; nt < 4; ++nt) lacc[mt][nt] = (float4v){0.f, 0.f, 0.f, 0.f};
        #pragma unroll
        for (int kq = 0; kq < 8; ++kq) {
            #pragma unroll
            for (int nt = 0; nt < 4; ++nt) {
                const short8 kf = *(const short8*)&KfL[((nt * 8 + kq) * 64 + lane) * 8];
                lacc[0][nt] = __builtin_amdgcn_mfma_f32_16x16x32_bf16(qf[0][kq], kf, lacc[0][nt], 0, 0, 0);
                lacc[1][nt] = __builtin_amdgcn_mfma_f32_16x16x32_bf16(qf[1][kq], kf, lacc[1][nt], 0, 0, 0);
            }
        }
        #pragma unroll
        for (int mt = 0; mt < 2; ++mt) {
            #pragma unroll
            for (int reg = 0; reg < 4; ++reg) {
                const float l0 = lacc[mt][0][reg], l1 = lacc[mt][1][reg];
                const float l2 = lacc[mt][2][reg], l3 = lacc[mt][3][reg];
                float m = fmaxf(fmaxf(l0, l1), fmaxf(l2, l3));
                m = fmaxf(m, __shfl_xor(m, 1));
                m = fmaxf(m, __shfl_xor(m, 2));
                m = fmaxf(m, __shfl_xor(m, 4));
                m = fmaxf(m, __shfl_xor(m, 8));
                const float e0 = __expf(l0 - m), e1 = __expf(l1 - m);
                const float e2 = __expf(l2 - m), e3 = __expf(l3 - m);
                float s = e0 + e1 + e2 + e3;
                s += __shfl_xor(s, 1);
                s += __shfl_xor(s, 2);
                s += __shfl_xor(s, 4);
                s += __shfl_xor(s, 8);
                const float inv = 1.f / s;
                const int lt = qd * 4 + reg;
                const int jj = lm & 7;
                const int lsub = lt + 16 * (lm >> 3);
                PfL[wpf + ((mt * 2 + 0) * 64 + lsub) * 8 + jj]      = f2bf(e0 * inv);
                PfL[wpf + ((mt * 2 + 0) * 64 + lsub + 32) * 8 + jj] = f2bf(e1 * inv);
                PfL[wpf + ((mt * 2 + 1) * 64 + lsub) * 8 + jj]      = f2bf(e2 * inv);
                PfL[wpf + ((mt * 2 + 1) * 64 + lsub + 32) * 8 + jj] = f2bf(e3 * inv);
            }
        }
        #pragma unroll
        for (int kqv = 0; kqv < 2; ++kqv) {
            const short8 p0 = *(const short8*)&PfL[wpf + ((0 * 2 + kqv) * 64 + lane) * 8];
            const short8 p1 = *(const short8*)&PfL[wpf + ((1 * 2 + kqv) * 64 + lane) * 8];
            #pragma unroll
            for (int nt = 0; nt < 16; ++nt) {
                const short8 vf = *(const short8*)&VfL[((nt * 2 + kqv) * 64 + lane) * 8];
                pacc[0][nt] = __builtin_amdgcn_mfma_f32_16x16x32_bf16(p0, vf, pacc[0][nt], 0, 0, 0);
                pacc[1][nt] = __builtin_amdgcn_mfma_f32_16x16x32_bf16(p1, vf, pacc[1][nt], 0, 0, 0);
            }
        }
    }

    // remap (verified r6-r10): row = b*32 + h*16 + (t>>1), col = (t&1)*256 + d
    if (mode == 0) {
        unsigned short* part = partg + (size_t)c * 1048576;
        #pragma unroll
        for (int mt = 0; mt < 2; ++mt)
            #pragma unroll
            for (int nt = 0; nt < 16; ++nt) {
                const int d = nt * 16 + lm;
                #pragma unroll
                for (int reg = 0; reg < 4; ++reg) {
                    const int t = mt * 16 + qd * 4 + reg;
                    const int row = b * 32 + h * 16 + (t >> 1);
                    const int col = (t & 1) * 256 + d;
                    part[(size_t)row * 512 + col] = f2bf(pacc[mt][nt][reg]);
                }
            }
    } else {
        #pragma unroll
        for (int mt = 0; mt < 2; ++mt)
            #pragma unroll
            for (int nt = 0; nt < 16; ++nt) {
                const int d = nt * 16 + lm;
                #pragma unroll
                for (int reg = 0; reg < 4; ++reg) {
                    const int t = mt * 16 + qd * 4 + reg;
                    const int row = b * 32 + h * 16 + (t >> 1);
                    const int col = (t & 1) * 256 + d;
                    atomicAdd(&acc[(size_t)row * 512 + col], pacc[mt][nt][reg]);
                }
            }
    }
}

// ===========================================================================
// proj_o8: out = (sum/128) @ Wo^T + bo, fp32 out. Grid (64,8), 256 thr.
// mode 0: A = sum of 8 bf16 partials (reduction folded into staging, fp32 sum,
//         single rounding). mode 1: A = fp32 acc.
// ===========================================================================
__global__ __launch_bounds__(256)
void proj_o8(const unsigned short* __restrict__ partg, const float* __restrict__ acc,
             const float* __restrict__ W, const float* __restrict__ bias,
             float* __restrict__ C, int mode) {
    __shared__ __align__(16) unsigned short Ab[32][40];
    __shared__ __align__(16) unsigned short Wb[64][40];
    const int tid = threadIdx.x;
    const int bi = blockIdx.x * 32, bj = blockIdx.y * 64;
    const int w = tid >> 6, lane = tid & 63;
    const int lm = lane & 15, qd = lane >> 4;
    const int mt = w & 1, np = (w >> 1) * 2;

    float4v acc2[2];
    acc2[0] = (float4v){0.f, 0.f, 0.f, 0.f};
    acc2[1] = (float4v){0.f, 0.f, 0.f, 0.f};

    for (int k0 = 0; k0 < 512; k0 += 32) {
        {
            const int s = tid;
            const int r = s >> 3, c4 = (s & 7) * 4;
            float4v fa;
            if (mode == 0) {
                float s0 = 0.f, s1 = 0.f, s2 = 0.f, s3 = 0.f;
                const size_t off = (size_t)(bi + r) * 512 + k0 + c4;
                #pragma unroll
                for (int p = 0; p < 8; ++p) {
                    ushort4v u = *(const ushort4v*)&partg[(size_t)p * 1048576 + off];
                    s0 += bf2f(u[0]); s1 += bf2f(u[1]); s2 += bf2f(u[2]); s3 += bf2f(u[3]);
                }
                fa = (float4v){s0, s1, s2, s3};
            } else {
                fa = *(const float4v*)&acc[(size_t)(bi + r) * 512 + k0 + c4];
            }
            fa *= 0.0078125f;   // 1/128 mean
            *(ushort4v*)&Ab[r][c4] = (ushort4v){f2bf(fa.x), f2bf(fa.y), f2bf(fa.z), f2bf(fa.w)};
        }
        #pragma unroll
        for (int it = 0; it < 2; ++it) {
            const int s = tid + it * 256;
            const int r = s >> 3, c4 = (s & 7) * 4;
            float4v fw = *(const float4v*)&W[(size_t)(bj + r) * 512 + k0 + c4];
            *(ushort4v*)&Wb[r][c4] = (ushort4v){f2bf(fw.x), f2bf(fw.y), f2bf(fw.z), f2bf(fw.w)};
        }
        __syncthreads();
        const short8 af = *(const short8*)&Ab[mt * 16 + lm][qd * 8];
        #pragma unroll
        for (int j = 0; j < 2; ++j) {
            const short8 bf = *(const short8*)&Wb[(np + j) * 16 + lm][qd * 8];
            acc2[j] = __builtin_amdgcn_mfma_f32_16x16x32_bf16(af, bf, acc2[j], 0, 0, 0);
        }
        __syncthreads();
    }
    #pragma unroll
    for (int j = 0; j < 2; ++j) {
        const int c = bj + (np + j) * 16 + lm;
        const float bb = bias[c];
        #pragma unroll
        for (int reg = 0; reg < 4; ++reg) {
            const int r = bi + mt * 16 + qd * 4 + reg;
            C[(size_t)r * 512 + c] = acc2[j][reg] + bb;
        }
    }
}

extern "C" void kernel_launch(void* const* d_in, const int* in_sizes, int n_in,
                              void* d_out, int out_size, void* d_ws, size_t ws_size,
                              hipStream_t stream) {
    const float* text  = (const float*)d_in[0];
    const float* video = (const float*)d_in[1];
    const float* Wq = (const float*)d_in[2];
    const float* bq = (const float*)d_in[3];
    const float* Wk = (const float*)d_in[4];
    const float* bk = (const float*)d_in[5];
    const float* Wv = (const float*)d_in[6];
    const float* bv = (const float*)d_in[7];
    const float* Wo = (const float*)d_in[8];
    const float* bo = (const float*)d_in[9];

    // ws layout: Kgf 8 MB @0; Vgf 8 MB @8MB; then EITHER
    //   mode 0 (ws >= 32 MB): partg bf16 [8][2048][512] @16MB (16 MB), no atomics
    //   mode 1 (ws >= 20 MB): acc fp32 [2048][512] @16MB (4 MB), 8.4M atomics
    // q bf16 [2048][512] (pre-scaled 1/16) in d_out [0,2MB), consumed by attn16
    // before proj_o8 overwrites d_out.
    unsigned short* Kgf   = (unsigned short*)d_ws;
    unsigned short* Vgf   = (unsigned short*)((char*)d_ws + (8u << 20));
    unsigned short* partg = (unsigned short*)((char*)d_ws + (16u << 20));
    float*          acc   = (float*)((char*)d_ws + (16u << 20));
    unsigned short* qbf   = (unsigned short*)d_out;
    float*          out   = (float*)d_out;

    const int mode = (ws_size >= (32ull << 20)) ? 0 : 1;

    proj_qkv<<<dim3(288, 8), 256, 0, stream>>>(text, video, Wq, bq, Wk, bk, Wv, bv,
                                               qbf, Kgf, Vgf);
    if (mode == 1)
        hipMemsetAsync(acc, 0, 1u << 22, stream);
    attn16<<<dim3(8, 2, 16), 256, 0, stream>>>(Kgf, Vgf, qbf, partg, acc, mode);
    proj_o8<<<dim3(64, 8), 256, 0, stream>>>(partg, acc, Wo, bo, out, mode);
}

// Round 12
// 186.461 us; speedup vs baseline: 1.5213x; 1.5213x over previous
//
#include <hip/hip_runtime.h>
#include <hip/hip_bf16.h>
#include <math.h>

#define EMBED  512
#define HEADS  2
#define HDIM   256
#define NTEXT  64
#define NWORD  32
#define NVID   128
#define NFRM   64

typedef __attribute__((ext_vector_type(8))) short      short8;    // 8 bf16 = A/B frag
typedef __attribute__((ext_vector_type(8))) unsigned short ushort8;
typedef __attribute__((ext_vector_type(4))) float      float4v;   // C/D frag
typedef __attribute__((ext_vector_type(4))) unsigned short ushort4v;

__device__ __forceinline__ unsigned short f2bf(float x) {
    __hip_bfloat16 h = __float2bfloat16(x);
    return *(unsigned short*)&h;
}
__device__ __forceinline__ float bf2f(unsigned short u) {
    __hip_bfloat16 h = *(__hip_bfloat16*)&u;
    return __bfloat162float(h);
}

// ===========================================================================
// proj_qkv v2: unified projection GEMM, KSTEP=64 (half the barriers of r11).
// Grid (288, 8), 256 thr. Outputs identical to r11 (verified):
//   mb <  32 : q  = (text @ Wq^T + bq)/16 -> bf16 row-major [2048][512] (d_out)
//   mb < 160 : K  -> frag-major Kgf[h][a][nt4][kq8][l64][j8]
//   else     : V  -> frag-major Vgf[h][a][ntd16][kqv2][l64][j8]
// ===========================================================================
__global__ __launch_bounds__(256)
void proj_qkv(const float* __restrict__ text, const float* __restrict__ video,
              const float* __restrict__ Wq, const float* __restrict__ bq,
              const float* __restrict__ Wk, const float* __restrict__ bk,
              const float* __restrict__ Wv, const float* __restrict__ bv,
              unsigned short* __restrict__ qout,
              unsigned short* __restrict__ Kgf, unsigned short* __restrict__ Vgf) {
    const int mb = blockIdx.x, nb = blockIdx.y;
    const int bj = nb * 64;
    const float *A, *W, *bias;
    int op, arow, a = 0;
    if (mb < 32)       { op = 0; A = text;  W = Wq; bias = bq; arow = mb * 64; }
    else if (mb < 160) { op = 1; A = video; W = Wk; bias = bk; a = mb - 32;  arow = a * 64; }
    else               { op = 2; A = video; W = Wv; bias = bv; a = mb - 160; arow = a * 64; }

    // Ab[64][72] + Wb[64][72] bf16 = 18432 B; Eb[64][72] unions Ab (epilogue)
    __shared__ __align__(16) unsigned char smem[64 * 72 * 2 * 2];
    unsigned short (*Ab)[72] = (unsigned short (*)[72])smem;
    unsigned short (*Wb)[72] = (unsigned short (*)[72])(smem + 64 * 72 * 2);
    unsigned short (*Eb)[72] = (unsigned short (*)[72])smem;

    const int tid = threadIdx.x;
    const int w = tid >> 6, lane = tid & 63;
    const int lm = lane & 15, qd = lane >> 4;

    float4v acc[4];
    #pragma unroll
    for (int nt = 0; nt < 4; ++nt) acc[nt] = (float4v){0.f, 0.f, 0.f, 0.f};

    for (int k0 = 0; k0 < 512; k0 += 64) {
        #pragma unroll
        for (int it = 0; it < 4; ++it) {
            const int s = tid + it * 256;          // 0..1023 float4 slots
            const int r = s >> 4, c4 = (s & 15) * 4;
            float4v fa = *(const float4v*)&A[(size_t)(arow + r) * 512 + k0 + c4];
            float4v fw = *(const float4v*)&W[(size_t)(bj + r) * 512 + k0 + c4];
            *(ushort4v*)&Ab[r][c4] = (ushort4v){f2bf(fa.x), f2bf(fa.y), f2bf(fa.z), f2bf(fa.w)};
            *(ushort4v*)&Wb[r][c4] = (ushort4v){f2bf(fw.x), f2bf(fw.y), f2bf(fw.z), f2bf(fw.w)};
        }
        __syncthreads();
        #pragma unroll
        for (int kq = 0; kq < 2; ++kq) {
            const short8 af = *(const short8*)&Ab[w * 16 + lm][kq * 32 + qd * 8];
            #pragma unroll
            for (int nt = 0; nt < 4; ++nt) {
                const short8 bf = *(const short8*)&Wb[nt * 16 + lm][kq * 32 + qd * 8];
                acc[nt] = __builtin_amdgcn_mfma_f32_16x16x32_bf16(af, bf, acc[nt], 0, 0, 0);
            }
        }
        __syncthreads();
    }

    if (op == 0) {
        #pragma unroll
        for (int nt = 0; nt < 4; ++nt) {
            const int c = bj + nt * 16 + lm;
            const float bb = bias[c];
            #pragma unroll
            for (int reg = 0; reg < 4; ++reg) {
                const int r = arow + w * 16 + qd * 4 + reg;
                qout[(size_t)r * 512 + c] = f2bf((acc[nt][reg] + bb) * 0.0625f);
            }
        }
        return;
    }

    const int h = bj >> 8;
    const int bj_rel = bj & 255;

    if (op == 1) {
        #pragma unroll
        for (int nt = 0; nt < 4; ++nt) {
            const int dl = nt * 16 + lm;
            const float bb = bias[bj + dl];
            #pragma unroll
            for (int reg = 0; reg < 4; ++reg)
                Eb[w * 16 + qd * 4 + reg][dl] = f2bf(acc[nt][reg] + bb);
        }
        __syncthreads();
        const size_t base = ((size_t)(h * 128 + a)) * 16384;
        #pragma unroll
        for (int i = 0; i < 2; ++i) {
            const int s = tid + i * 256;
            const int ntf = s >> 7, kqr = (s >> 6) & 1, l = s & 63;
            const int v = ntf * 16 + (l & 15);
            const int dl = kqr * 32 + (l >> 4) * 8;
            ushort8 val = *(const ushort8*)&Eb[v][dl];
            *(ushort8*)&Kgf[base + ((size_t)(ntf * 8 + (bj_rel >> 5) + kqr) * 64 + l) * 8] = val;
        }
    } else {
        #pragma unroll
        for (int nt = 0; nt < 4; ++nt) {
            const int dl = nt * 16 + lm;
            const float bb = bias[bj + dl];
            #pragma unroll
            for (int reg = 0; reg < 4; ++reg)
                Eb[dl][w * 16 + qd * 4 + reg] = f2bf(acc[nt][reg] + bb);
        }
        __syncthreads();
        const size_t base = ((size_t)(h * 128 + a)) * 16384;
        #pragma unroll
        for (int i = 0; i < 2; ++i) {
            const int s = tid + i * 256;
            const int ntr = s >> 7, kqv = (s >> 6) & 1, l = s & 63;
            const int dl = ntr * 16 + (l & 15);
            const int v0 = kqv * 32 + (l >> 4) * 8;
            ushort8 val = *(const ushort8*)&Eb[dl][v0];
            *(ushort8*)&Vgf[base + ((size_t)(((bj_rel >> 4) + ntr) * 2 + kqv) * 64 + l) * 8] = val;
        }
    }
}

// ===========================================================================
// attn8: grid (8 chunks, 2 h, 16 tg) = 256 blocks, 512 thr (8 waves), 1/CU.
// Wave w: text b = tg*4 + (w>>1), row-half wm = w&1 (16 t-rows). 16 vids per
// block; one 64 KB K/V stage per vid feeds all 8 waves. Register prefetch:
// vid i+1 loaded into VGPRs during compute of vid i, ds_written next iter.
// r9/r11-verified MFMA math; zero atomics; bf16 partial store (partials[8]).
// ===========================================================================
__global__ __launch_bounds__(512, 2)
void attn8(const unsigned short* __restrict__ Kgf,
           const unsigned short* __restrict__ Vgf,
           const unsigned short* __restrict__ q,   // bf16, pre-scaled 1/16
           unsigned short* __restrict__ partg) {   // [8][2048][512] bf16
    const int c  = blockIdx.x;
    const int h  = blockIdx.y;
    const int tg = blockIdx.z;
    const int tid = threadIdx.x;
    const int w = tid >> 6, lane = tid & 63;
    const int lm = lane & 15, qd = lane >> 4;
    const int wt = w >> 1, wm = w & 1;
    const int b = tg * 4 + wt;

    __shared__ __align__(16) unsigned short KfL[16384];   // 32 KB
    __shared__ __align__(16) unsigned short VfL[16384];   // 32 KB
    __shared__ __align__(16) unsigned short PfL[8192];    // 16 KB (2 KB/wave)
    const int wpf = w * 1024;

    // Q A-frags for this wave's 16 rows: 8 frags = 32 VGPRs
    short8 qf[8];
    #pragma unroll
    for (int kq = 0; kq < 8; ++kq)
        qf[kq] = *(const short8*)
            &q[((size_t)(b * 32 + wm * 16 + lm)) * 512 + h * 256 + kq * 32 + qd * 8];

    float4v pacc[16];
    #pragma unroll
    for (int nt = 0; nt < 16; ++nt) pacc[nt] = (float4v){0.f, 0.f, 0.f, 0.f};

    // prefetch vid 0 into regs (32 VGPRs)
    ushort8 rK[4], rV[4];
    {
        const size_t kb = ((size_t)(h * 128 + c * 16)) * 16384;
        #pragma unroll
        for (int i = 0; i < 4; ++i) {
            const int s = tid + i * 512;
            rK[i] = *(const ushort8*)&Kgf[kb + (size_t)s * 8];
            rV[i] = *(const ushort8*)&Vgf[kb + (size_t)s * 8];
        }
    }

    for (int ai = 0; ai < 16; ++ai) {
        __syncthreads();   // all waves done reading previous K/V
        #pragma unroll
        for (int i = 0; i < 4; ++i) {
            const int s = tid + i * 512;
            *(ushort8*)&KfL[s * 8] = rK[i];
            *(ushort8*)&VfL[s * 8] = rV[i];
        }
        __syncthreads();   // staged data visible
        if (ai < 15) {     // prefetch next vid; overlaps the MFMA stream below
            const size_t kb = ((size_t)(h * 128 + c * 16 + ai + 1)) * 16384;
            #pragma unroll
            for (int i = 0; i < 4; ++i) {
                const int s = tid + i * 512;
                rK[i] = *(const ushort8*)&Kgf[kb + (size_t)s * 8];
                rV[i] = *(const ushort8*)&Vgf[kb + (size_t)s * 8];
            }
        }

        // QK: logits for this wave's 16 rows (q pre-scaled by 1/16)
        float4v lacc[4];
        #pragma unroll
        for (int nt = 0; nt < 4; ++nt) lacc[nt] = (float4v){0.f, 0.f, 0.f, 0.f};
        #pragma unroll
        for (int kq = 0; kq < 8; ++kq) {
            #pragma unroll
            for (int nt = 0; nt < 4; ++nt) {
                const short8 kf = *(const short8*)&KfL[((nt * 8 + kq) * 64 + lane) * 8];
                lacc[nt] = __builtin_amdgcn_mfma_f32_16x16x32_bf16(qf[kq], kf, lacc[nt], 0, 0, 0);
            }
        }
        // softmax over v (4 nt in-lane x 16 lm cross-lane) per row
        #pragma unroll
        for (int reg = 0; reg < 4; ++reg) {
            const float l0 = lacc[0][reg], l1 = lacc[1][reg];
            const float l2 = lacc[2][reg], l3 = lacc[3][reg];
            float m = fmaxf(fmaxf(l0, l1), fmaxf(l2, l3));
            m = fmaxf(m, __shfl_xor(m, 1));
            m = fmaxf(m, __shfl_xor(m, 2));
            m = fmaxf(m, __shfl_xor(m, 4));
            m = fmaxf(m, __shfl_xor(m, 8));
            const float e0 = __expf(l0 - m), e1 = __expf(l1 - m);
            const float e2 = __expf(l2 - m), e3 = __expf(l3 - m);
            float s = e0 + e1 + e2 + e3;
            s += __shfl_xor(s, 1);
            s += __shfl_xor(s, 2);
            s += __shfl_xor(s, 4);
            s += __shfl_xor(s, 8);
            const float inv = 1.f / s;
            const int lt = qd * 4 + reg;
            const int jj = lm & 7;
            const int lsub = lt + 16 * (lm >> 3);
            PfL[wpf + (0 * 64 + lsub) * 8 + jj]      = f2bf(e0 * inv);  // nt0 -> kqv0
            PfL[wpf + (0 * 64 + lsub + 32) * 8 + jj] = f2bf(e1 * inv);  // nt1 -> kqv0
            PfL[wpf + (1 * 64 + lsub) * 8 + jj]      = f2bf(e2 * inv);  // nt2 -> kqv1
            PfL[wpf + (1 * 64 + lsub + 32) * 8 + jj] = f2bf(e3 * inv);  // nt3 -> kqv1
        }
        // PV: accumulate in registers (wave-private P patch, no barrier)
        #pragma unroll
        for (int kqv = 0; kqv < 2; ++kqv) {
            const short8 pf = *(const short8*)&PfL[wpf + (kqv * 64 + lane) * 8];
            #pragma unroll
            for (int nt = 0; nt < 16; ++nt) {
                const short8 vf = *(const short8*)&VfL[((nt * 2 + kqv) * 64 + lane) * 8];
                pacc[nt] = __builtin_amdgcn_mfma_f32_16x16x32_bf16(pf, vf, pacc[nt], 0, 0, 0);
            }
        }
    }

    // bf16 partial store (remap verified r6-r11): row = b*32 + h*16 + (t>>1),
    // col = (t&1)*256 + d, t = wm*16 + qd*4 + reg
    unsigned short* part = partg + (size_t)c * 1048576;
    #pragma unroll
    for (int nt = 0; nt < 16; ++nt) {
        const int d = nt * 16 + lm;
        #pragma unroll
        for (int reg = 0; reg < 4; ++reg) {
            const int t = wm * 16 + qd * 4 + reg;
            const int row = b * 32 + h * 16 + (t >> 1);
            const int col = (t & 1) * 256 + d;
            part[(size_t)row * 512 + col] = f2bf(pacc[nt][reg]);
        }
    }
}

// ===========================================================================
// reduce8: elementwise, in-place: partg[0][i] = (sum_p partg[p][i]) / 128,
// bf16 (single rounding). Grid 512 x 256 thr, 8 elements/thread.
// ===========================================================================
__global__ __launch_bounds__(256)
void reduce8(unsigned short* __restrict__ partg) {
    const size_t i = ((size_t)blockIdx.x * 256 + threadIdx.x) * 8;
    float s[8];
    #pragma unroll
    for (int j = 0; j < 8; ++j) s[j] = 0.f;
    #pragma unroll
    for (int p = 0; p < 8; ++p) {
        ushort8 u = *(const ushort8*)&partg[(size_t)p * 1048576 + i];
        #pragma unroll
        for (int j = 0; j < 8; ++j) s[j] += bf2f(u[j]);
    }
    ushort8 o;
    #pragma unroll
    for (int j = 0; j < 8; ++j) o[j] = f2bf(s[j] * 0.0078125f);
    *(ushort8*)&partg[i] = o;
}

// ===========================================================================
// proj_o: out = Abf @ Wo^T + bo, fp32 out. Abf = reduced bf16 [2048][512]
// (already scaled 1/128). KSTEP 64, 64x64 tiles, grid (32, 8).
// ===========================================================================
__global__ __launch_bounds__(256)
void proj_o(const unsigned short* __restrict__ Abf, const float* __restrict__ W,
            const float* __restrict__ bias, float* __restrict__ C) {
    __shared__ __align__(16) unsigned short Ab[64][72];
    __shared__ __align__(16) unsigned short Wb[64][72];
    const int tid = threadIdx.x;
    const int bi = blockIdx.x * 64, bj = blockIdx.y * 64;
    const int w = tid >> 6, lane = tid & 63;
    const int lm = lane & 15, qd = lane >> 4;

    float4v acc[4];
    #pragma unroll
    for (int nt = 0; nt < 4; ++nt) acc[nt] = (float4v){0.f, 0.f, 0.f, 0.f};

    for (int k0 = 0; k0 < 512; k0 += 64) {
        #pragma unroll
        for (int it = 0; it < 2; ++it) {           // A: bf16 copy, 512 ushort8 slots
            const int s = tid + it * 256;
            const int r = s >> 3, c8 = (s & 7) * 8;
            *(ushort8*)&Ab[r][c8] = *(const ushort8*)&Abf[(size_t)(bi + r) * 512 + k0 + c8];
        }
        #pragma unroll
        for (int it = 0; it < 4; ++it) {           // W: fp32 -> bf16
            const int s = tid + it * 256;
            const int r = s >> 4, c4 = (s & 15) * 4;
            float4v fw = *(const float4v*)&W[(size_t)(bj + r) * 512 + k0 + c4];
            *(ushort4v*)&Wb[r][c4] = (ushort4v){f2bf(fw.x), f2bf(fw.y), f2bf(fw.z), f2bf(fw.w)};
        }
        __syncthreads();
        #pragma unroll
        for (int kq = 0; kq < 2; ++kq) {
            const short8 af = *(const short8*)&Ab[w * 16 + lm][kq * 32 + qd * 8];
            #pragma unroll
            for (int nt = 0; nt < 4; ++nt) {
                const short8 bf = *(const short8*)&Wb[nt * 16 + lm][kq * 32 + qd * 8];
                acc[nt] = __builtin_amdgcn_mfma_f32_16x16x32_bf16(af, bf, acc[nt], 0, 0, 0);
            }
        }
        __syncthreads();
    }
    #pragma unroll
    for (int nt = 0; nt < 4; ++nt) {
        const int cc = bj + nt * 16 + lm;
        const float bb = bias[cc];
        #pragma unroll
        for (int reg = 0; reg < 4; ++reg) {
            const int r = bi + w * 16 + qd * 4 + reg;
            C[(size_t)r * 512 + cc] = acc[nt][reg] + bb;
        }
    }
}

extern "C" void kernel_launch(void* const* d_in, const int* in_sizes, int n_in,
                              void* d_out, int out_size, void* d_ws, size_t ws_size,
                              hipStream_t stream) {
    const float* text  = (const float*)d_in[0];
    const float* video = (const float*)d_in[1];
    const float* Wq = (const float*)d_in[2];
    const float* bq = (const float*)d_in[3];
    const float* Wk = (const float*)d_in[4];
    const float* bk = (const float*)d_in[5];
    const float* Wv = (const float*)d_in[6];
    const float* bv = (const float*)d_in[7];
    const float* Wo = (const float*)d_in[8];
    const float* bo = (const float*)d_in[9];

    // ws (32 MB, proven in r11): Kgf 8 MB @0; Vgf 8 MB @8MB;
    // partg bf16 [8][2048][512] @16MB (16 MB; partg[0] becomes the reduced mean).
    // q bf16 [2048][512] (pre-scaled 1/16) in d_out [0,2MB), consumed by attn8
    // before proj_o overwrites d_out.
    unsigned short* Kgf   = (unsigned short*)d_ws;
    unsigned short* Vgf   = (unsigned short*)((char*)d_ws + (8u << 20));
    unsigned short* partg = (unsigned short*)((char*)d_ws + (16u << 20));
    unsigned short* qbf   = (unsigned short*)d_out;
    float*          out   = (float*)d_out;

    proj_qkv<<<dim3(288, 8), 256, 0, stream>>>(text, video, Wq, bq, Wk, bk, Wv, bv,
                                               qbf, Kgf, Vgf);
    attn8<<<dim3(8, 2, 16), 512, 0, stream>>>(Kgf, Vgf, qbf, partg);
    reduce8<<<dim3(512), 256, 0, stream>>>(partg);
    proj_o<<<dim3(32, 8), 256, 0, stream>>>(partg, Wo, bo, out);
}